// Round 10
// baseline (111.838 us; speedup 1.0000x reference)
//
#include <hip/hip_runtime.h>
#include <math.h>

#define B 8
#define C 64
#define HH 64
#define WW 64
#define N 4096
#define CR 8

typedef __attribute__((ext_vector_type(8))) short short8;
typedef __attribute__((ext_vector_type(4))) float f32x4;

__device__ __forceinline__ float sigmoidf_(float x) { return 1.0f / (1.0f + __expf(-x)); }

// round-float-to-bf16 bits (round-half-up; inputs are finite, well-scaled)
__device__ __forceinline__ unsigned int bfr_(float x) {
    return (__float_as_uint(x) + 0x8000u) >> 16;
}

// ---------------------------------------------------------------------------
// Shared helper: per-batch channel-attention MLP, recomputed redundantly per
// block (2K FLOPs). Requires 256 threads; leaves result in lca[C].
// ---------------------------------------------------------------------------
__device__ __forceinline__ void compute_ca_(const float* __restrict__ avg,
                                            const float* __restrict__ mx,
                                            const float* __restrict__ fc1,
                                            const float* __restrict__ fc2,
                                            int b, float* lca, float* lh) {
    int t = threadIdx.x;
    if (t < 16) {
        int r = t & 7;
        const float* src = (t < 8) ? (avg + b * C) : (mx + b * C);
        float acc = 0.f;
        for (int c2 = 0; c2 < C; c2++) acc += src[c2] * fc1[r * C + c2];
        lh[t] = fmaxf(acc, 0.f);
    }
    __syncthreads();
    if (t < C) {
        float acc = 0.f;
        #pragma unroll
        for (int r = 0; r < CR; r++) acc += (lh[r] + lh[CR + r]) * fc2[t * CR + r];
        lca[t] = sigmoidf_(acc);
    }
    __syncthreads();
}

// ---------------------------------------------------------------------------
// K1: per-(b,c) mean/max reduction  ∪  QKV projection (gamma!=0 only).
// grid (64, 8) x 256.
// ---------------------------------------------------------------------------
__global__ __launch_bounds__(256) void k_red_qkv(const float* __restrict__ x,
                                                 const float* __restrict__ qw, const float* __restrict__ qb,
                                                 const float* __restrict__ kw, const float* __restrict__ kb,
                                                 const float* __restrict__ vw, const float* __restrict__ vb,
                                                 const float* __restrict__ gamma,
                                                 float* __restrict__ avg, float* __restrict__ mx,
                                                 unsigned short* __restrict__ qT,
                                                 unsigned short* __restrict__ kT,
                                                 unsigned short* __restrict__ vbf) {
    const int b = blockIdx.y, cx = blockIdx.x;
    const int t = threadIdx.x;
    {
        const float4* xp = (const float4*)(x + ((size_t)b * C + cx) * N);
        float s = 0.f, m = -INFINITY;
        for (int i = t; i < N / 4; i += 256) {
            float4 v = xp[i];
            s += v.x + v.y + v.z + v.w;
            m = fmaxf(m, fmaxf(fmaxf(v.x, v.y), fmaxf(v.z, v.w)));
        }
        for (int off = 32; off; off >>= 1) {
            s += __shfl_down(s, off);
            m = fmaxf(m, __shfl_down(m, off));
        }
        __shared__ float ls[4], lm[4];
        int wave = t >> 6;
        if ((t & 63) == 0) { ls[wave] = s; lm[wave] = m; }
        __syncthreads();
        if (t == 0) {
            avg[b * C + cx] = (ls[0] + ls[1] + ls[2] + ls[3]) / (float)N;
            mx[b * C + cx] = fmaxf(fmaxf(lm[0], lm[1]), fmaxf(lm[2], lm[3]));
        }
    }
    if (gamma[0] == 0.f) return;  // PAM branch contributes 0; QKV outputs unused
    __shared__ float xl[C][64];
    __shared__ float vwt[C][68];
    __shared__ float qwl[CR * C], kwl[CR * C];
    const int p0 = cx * 64;
    for (int idx = t; idx < C * 64; idx += 256) {
        int c2 = idx >> 6, pix = idx & 63;
        xl[c2][pix] = x[((size_t)b * C + c2) * N + p0 + pix];
    }
    for (int idx = t; idx < C * C; idx += 256) {
        int co = idx >> 6, ci = idx & 63;
        vwt[ci][co] = vw[idx];
    }
    for (int idx = t; idx < CR * C; idx += 256) {
        qwl[idx] = qw[idx];
        kwl[idx] = kw[idx];
    }
    __syncthreads();
    int pix = t & 63, quarter = t >> 6;
    float accv[16];
    #pragma unroll
    for (int i = 0; i < 16; i++) accv[i] = 0.f;
    float accq0 = 0.f, accq1 = 0.f, acck0 = 0.f, acck1 = 0.f;
    for (int ci = 0; ci < C; ci++) {
        float xv = xl[ci][pix];
        accq0 += qwl[(quarter * 2 + 0) * C + ci] * xv;
        accq1 += qwl[(quarter * 2 + 1) * C + ci] * xv;
        acck0 += kwl[(quarter * 2 + 0) * C + ci] * xv;
        acck1 += kwl[(quarter * 2 + 1) * C + ci] * xv;
        const float4* row = (const float4*)&vwt[ci][quarter * 16];
        #pragma unroll
        for (int m2 = 0; m2 < 4; m2++) {
            float4 w4 = row[m2];
            accv[m2 * 4 + 0] += w4.x * xv;
            accv[m2 * 4 + 1] += w4.y * xv;
            accv[m2 * 4 + 2] += w4.z * xv;
            accv[m2 * 4 + 3] += w4.w * xv;
        }
    }
    int pg = p0 + pix;
    int r0 = quarter * 2;
    unsigned int qpk = bfr_(accq0 + qb[r0]) | (bfr_(accq1 + qb[r0 + 1]) << 16);
    unsigned int kpk = bfr_(acck0 + kb[r0]) | (bfr_(acck1 + kb[r0 + 1]) << 16);
    *(unsigned int*)(qT + ((size_t)b * N + pg) * 8 + r0) = qpk;
    *(unsigned int*)(kT + ((size_t)b * N + pg) * 8 + r0) = kpk;
    #pragma unroll
    for (int i = 0; i < 16; i++) {
        int co = quarter * 16 + i;
        vbf[((size_t)b * C + co) * N + pg] = (unsigned short)bfr_(accv[i] + vb[co]);
    }
}

// ---------------------------------------------------------------------------
// K2: grid (32, B, S) x 256.
//  z==0, gamma==0: FULLY fused tail — halo stats (8 rows, <=4x redundant,
//    L2-warm) + 7x7 conv + sigmoid + final out write for rows [2bx, 2bx+1].
//  z==0, gamma!=0: ca-MLP + stats for own 128 pixels -> avg_s/max_s, then
//    flash body. z>0: flash body only (exit when gamma==0).
// Flash body identical to round-7/8 passing version (kf zero-init is
// load-bearing: stale-register NaN*0=NaN inside MFMA).
// ---------------------------------------------------------------------------
template <int S>
__global__ __launch_bounds__(256, 2) void k_stats_flash(
    const float* __restrict__ x,
    const float* __restrict__ avg, const float* __restrict__ mx,
    const float* __restrict__ fc1, const float* __restrict__ fc2,
    const float* __restrict__ saw,
    const float* __restrict__ gamma,
    const unsigned short* __restrict__ qT,
    const unsigned short* __restrict__ kT,
    const unsigned short* __restrict__ vbf,
    float* __restrict__ avg_s, float* __restrict__ max_s,
    float* __restrict__ pA, float* __restrict__ pM, float* __restrict__ pL,
    float* __restrict__ out) {
    __shared__ unsigned short p_lds[4][32 * 64];  // flash P buffer, per-wave 4KB
    __shared__ float lca[C], lh[16];
    __shared__ float xtile[C][128];               // own x rows (gamma==0 path)
    __shared__ float sA2[512], sM2[512], ssgl[128], lwp[98];
    const int b = blockIdx.y, p = blockIdx.z;
    const int tid = threadIdx.x;
    if (p == 0) {
        if (tid < 98) lwp[tid] = saw[tid];
        compute_ca_(avg, mx, fc1, fc2, b, lca, lh);
        if (gamma[0] == 0.f) {
            // ---- fused stats+conv+out for rows 2bx, 2bx+1 ----
            const int bx = blockIdx.x;
            const int r0 = 2 * bx - 3;                 // first halo row
            const int sp0 = tid, sp1 = tid + 256;      // stat-pixel indices [0,512)
            const int grow0 = r0 + (sp0 >> 6), gcol0 = sp0 & 63;
            const int grow1 = r0 + (sp1 >> 6), gcol1 = sp1 & 63;
            const bool v0 = (grow0 >= 0) && (grow0 < HH);
            const bool v1 = (grow1 >= 0) && (grow1 < HH);
            const float* xb = x + (size_t)b * C * N;
            float s0 = 0.f, s1 = 0.f, m0 = -INFINITY, m1 = -INFINITY;
            #pragma unroll 4
            for (int c = 0; c < C; c++) {
                float xv0 = v0 ? xb[(size_t)c * N + grow0 * WW + gcol0] : 0.f;
                float xv1 = v1 ? xb[(size_t)c * N + grow1 * WW + gcol1] : 0.f;
                if (sp0 >= 192 && sp0 < 320) xtile[c][sp0 - 192] = xv0;
                if (sp1 >= 192 && sp1 < 320) xtile[c][sp1 - 192] = xv1;
                float a0 = xv0 * lca[c], a1 = xv1 * lca[c];
                s0 += a0; s1 += a1;
                m0 = fmaxf(m0, a0); m1 = fmaxf(m1, a1);
            }
            sA2[sp0] = v0 ? s0 / (float)C : 0.f;
            sM2[sp0] = v0 ? m0 : 0.f;
            sA2[sp1] = v1 ? s1 / (float)C : 0.f;
            sM2[sp1] = v1 ? m1 : 0.f;
            __syncthreads();
            if (tid < 128) {
                int orow = tid >> 6, ocol = tid & 63;
                int srow = 3 + orow;  // stat-buffer row of this output pixel
                float acc = 0.f;
                #pragma unroll
                for (int ky = 0; ky < 7; ky++) {
                    #pragma unroll
                    for (int kx = 0; kx < 7; kx++) {
                        int wcol = ocol + kx - 3;
                        if (wcol < 0 || wcol >= WW) continue;
                        int idx = (srow + ky - 3) * 64 + wcol;
                        acc += sA2[idx] * lwp[ky * 7 + kx] + sM2[idx] * lwp[49 + ky * 7 + kx];
                    }
                }
                ssgl[tid] = sigmoidf_(acc);
            }
            __syncthreads();
            const int op = tid & 127, ch0 = (tid >> 7) * 32;
            const int obase = bx * 128;
            for (int c = ch0; c < ch0 + 32; c++) {
                size_t off = ((size_t)b * C + c) * N + obase + op;
                out[off] = xtile[c][op] * (1.f + lca[c] * ssgl[op]);
            }
            return;
        }
        // ---- gamma!=0: stats for own 128 pixels -> global maps ----
        int pix = blockIdx.x * 128 + (tid >> 1);
        int half = tid & 1;
        const float* xb = x + (size_t)b * C * N + pix;
        float s = 0.f, m = -INFINITY;
        for (int c = half * 32; c < half * 32 + 32; c++) {
            float v = xb[(size_t)c * N] * lca[c];
            s += v;
            m = fmaxf(m, v);
        }
        s += __shfl_xor(s, 1);
        m = fmaxf(m, __shfl_xor(m, 1));
        if (half == 0) {
            avg_s[b * N + pix] = s / (float)C;
            max_s[b * N + pix] = m;
        }
    }
    if (gamma[0] == 0.f) return;  // z>0 blocks: PAM branch contributes 0
    // --- flash body ---
    const int w = tid >> 6, lane = tid & 63;
    const int l16 = lane & 15, grp = lane >> 4;
    const int i0 = blockIdx.x * 128 + w * 32;
    char* pbase = (char*)&p_lds[w][0];
    const int swz = (l16 & 7) << 4;

    short8 qf[2];
    #pragma unroll
    for (int ifr = 0; ifr < 2; ifr++) {
        qf[ifr] = short8{};
        if (grp == 0) qf[ifr] = *(const short8*)(qT + ((size_t)b * N + i0 + ifr * 16 + l16) * 8);
    }
    f32x4 acc[2][4];
    #pragma unroll
    for (int ifr = 0; ifr < 2; ifr++)
        #pragma unroll
        for (int cf = 0; cf < 4; cf++) acc[ifr][cf] = f32x4{0.f, 0.f, 0.f, 0.f};
    float m[2] = {-INFINITY, -INFINITY}, l[2] = {0.f, 0.f};

    const int L = N / S;
    const int T = L / 64;
    const int jbase = p * L;
    const unsigned short* vbase = vbf + (size_t)b * C * N;
    const unsigned short* kbase = kT + (size_t)b * N * 8;

    short8 kf[2][4];
    #pragma unroll
    for (int ss = 0; ss < 2; ss++)
        #pragma unroll
        for (int jf = 0; jf < 4; jf++) kf[ss][jf] = short8{};
    #pragma unroll
    for (int jf = 0; jf < 4; jf++) {
        if (grp == 0) kf[0][jf] = *(const short8*)(kbase + (size_t)(jbase + jf * 16 + l16) * 8);
    }

    #pragma unroll 2
    for (int t = 0; t < T; t++) {
        const int cur = t & 1, nxt = cur ^ 1;
        const int j0 = jbase + t * 64;
        short8 vf[2][4];
        #pragma unroll
        for (int h = 0; h < 2; h++)
            #pragma unroll
            for (int cf = 0; cf < 4; cf++)
                vf[h][cf] = *(const short8*)(vbase + (size_t)(cf * 16 + l16) * N + j0 + h * 32 + grp * 8);
        if (t + 1 < T) {
            #pragma unroll
            for (int jf = 0; jf < 4; jf++) {
                if (grp == 0) kf[nxt][jf] = *(const short8*)(kbase + (size_t)(j0 + 64 + jf * 16 + l16) * 8);
            }
        }
        #pragma unroll
        for (int ifr = 0; ifr < 2; ifr++) {
            f32x4 e[4];
            #pragma unroll
            for (int jf = 0; jf < 4; jf++)
                e[jf] = __builtin_amdgcn_mfma_f32_16x16x32_bf16(kf[cur][jf], qf[ifr],
                                                                f32x4{0.f, 0.f, 0.f, 0.f}, 0, 0, 0);
            float tmax = -INFINITY;
            #pragma unroll
            for (int jf = 0; jf < 4; jf++)
                tmax = fmaxf(tmax, fmaxf(fmaxf(e[jf][0], e[jf][1]), fmaxf(e[jf][2], e[jf][3])));
            tmax = fmaxf(tmax, __shfl_xor(tmax, 16));
            tmax = fmaxf(tmax, __shfl_xor(tmax, 32));
            float mnew = fmaxf(m[ifr], tmax);
            float scale = __expf(m[ifr] - mnew);
            float ladd = 0.f;
            unsigned int pk[8];
            #pragma unroll
            for (int jf = 0; jf < 4; jf++) {
                float p0 = __expf(e[jf][0] - mnew);
                float p1 = __expf(e[jf][1] - mnew);
                float p2 = __expf(e[jf][2] - mnew);
                float p3 = __expf(e[jf][3] - mnew);
                ladd += (p0 + p1) + (p2 + p3);
                pk[jf * 2 + 0] = bfr_(p0) | (bfr_(p1) << 16);
                pk[jf * 2 + 1] = bfr_(p2) | (bfr_(p3) << 16);
            }
            ladd += __shfl_xor(ladd, 16);
            ladd += __shfl_xor(ladd, 32);
            l[ifr] = l[ifr] * scale + ladd;
            m[ifr] = mnew;
            #pragma unroll
            for (int cf = 0; cf < 4; cf++) {
                acc[ifr][cf][0] *= scale; acc[ifr][cf][1] *= scale;
                acc[ifr][cf][2] *= scale; acc[ifr][cf][3] *= scale;
            }
            const int rowoff = (ifr * 16 + l16) * 128;
            #pragma unroll
            for (int jf = 0; jf < 4; jf++) {
                int j = jf * 16 + grp * 4;
                *(unsigned int*)(pbase + ((rowoff + (j + 0) * 2) ^ swz)) = pk[jf * 2 + 0];
                *(unsigned int*)(pbase + ((rowoff + (j + 2) * 2) ^ swz)) = pk[jf * 2 + 1];
            }
        }
        #pragma unroll
        for (int ifr = 0; ifr < 2; ifr++) {
            const int rowoff = (ifr * 16 + l16) * 128;
            #pragma unroll
            for (int h = 0; h < 2; h++) {
                short8 pf = *(const short8*)(pbase + ((rowoff + (h * 32 + grp * 8) * 2) ^ swz));
                #pragma unroll
                for (int cf = 0; cf < 4; cf++)
                    acc[ifr][cf] = __builtin_amdgcn_mfma_f32_16x16x32_bf16(vf[h][cf], pf, acc[ifr][cf], 0, 0, 0);
            }
        }
    }
    const size_t plane = (size_t)(b * S + p);
    #pragma unroll
    for (int ifr = 0; ifr < 2; ifr++) {
        const int iglob = i0 + ifr * 16 + l16;
        #pragma unroll
        for (int cf = 0; cf < 4; cf++)
            #pragma unroll
            for (int r = 0; r < 4; r++)
                pA[(plane * C + cf * 16 + grp * 4 + r) * N + iglob] = acc[ifr][cf][r];
        if (grp == 0) {
            pM[plane * N + iglob] = m[ifr];
            pL[plane * N + iglob] = l[ifr];
        }
    }
}

// ---------------------------------------------------------------------------
// K3: gamma!=0 only — conv7x7+sigmoid from stats maps + ca + PAM combine.
// Stub (load gamma, return) when gamma==0: K2 already wrote out.
// ---------------------------------------------------------------------------
template <int S>
__global__ __launch_bounds__(256) void k_out(const float* __restrict__ x,
                                             const float* __restrict__ avg, const float* __restrict__ mx,
                                             const float* __restrict__ fc1, const float* __restrict__ fc2,
                                             const float* __restrict__ avg_s, const float* __restrict__ max_s,
                                             const float* __restrict__ saw,
                                             const float* __restrict__ gamma,
                                             const float* __restrict__ pA, const float* __restrict__ pM,
                                             const float* __restrict__ pL,
                                             float* __restrict__ out) {
    if (gamma[0] == 0.f) return;  // fully handled by K2's fused path
    const int b = blockIdx.y;
    const int i0 = blockIdx.x * 256;
    const int t = threadIdx.x;
    __shared__ float lca[C], lh[16], lw[98];
    __shared__ float sA[10 * 64], sM[10 * 64];
    if (t < 98) lw[t] = saw[t];
    compute_ca_(avg, mx, fc1, fc2, b, lca, lh);
    const int h0 = i0 >> 6;
    for (int idx = t; idx < 10 * 64; idx += 256) {
        int r = idx >> 6, wcol = idx & 63;
        int hh = h0 - 3 + r;
        float a = 0.f, mm2 = 0.f;
        if (hh >= 0 && hh < HH) {
            a = avg_s[b * N + hh * WW + wcol];
            mm2 = max_s[b * N + hh * WW + wcol];
        }
        sA[idx] = a;
        sM[idx] = mm2;
    }
    __syncthreads();
    const int lr = (t >> 6) + 3;
    const int wc = t & 63;
    float acc = 0.f;
    #pragma unroll
    for (int ky = 0; ky < 7; ky++) {
        #pragma unroll
        for (int kx = 0; kx < 7; kx++) {
            int ww = wc + kx - 3;
            if (ww < 0 || ww >= WW) continue;
            int idx = (lr + ky - 3) * 64 + ww;
            acc += sA[idx] * lw[ky * 7 + kx] + sM[idx] * lw[49 + ky * 7 + kx];
        }
    }
    const float sg = sigmoidf_(acc);
    const int i = i0 + t;
    const float g = gamma[0];
    float mm[S];
    float M = -INFINITY;
    #pragma unroll
    for (int p2 = 0; p2 < S; p2++) {
        mm[p2] = pM[(size_t)(b * S + p2) * N + i];
        M = fmaxf(M, mm[p2]);
    }
    float w[S];
    float lt = 0.f;
    #pragma unroll
    for (int p2 = 0; p2 < S; p2++) {
        w[p2] = __expf(mm[p2] - M);
        lt += w[p2] * pL[(size_t)(b * S + p2) * N + i];
    }
    float inv = 1.0f / lt;
    for (int c = 0; c < C; c++) {
        float a = 0.f;
        #pragma unroll
        for (int p2 = 0; p2 < S; p2++)
            a += w[p2] * pA[((size_t)(b * S + p2) * C + c) * N + i];
        float pam = a * inv;
        size_t off = ((size_t)b * C + c) * N + i;
        out[off] = x[off] * (1.f + lca[c] * sg) + g * pam;
    }
}

extern "C" void kernel_launch(void* const* d_in, const int* in_sizes, int n_in,
                              void* d_out, int out_size, void* d_ws, size_t ws_size,
                              hipStream_t stream) {
    (void)in_sizes; (void)n_in; (void)out_size;
    const float* x   = (const float*)d_in[0];
    const float* fc1 = (const float*)d_in[1];
    const float* fc2 = (const float*)d_in[2];
    const float* qw  = (const float*)d_in[3];
    const float* qb  = (const float*)d_in[4];
    const float* kw  = (const float*)d_in[5];
    const float* kb  = (const float*)d_in[6];
    const float* vw  = (const float*)d_in[7];
    const float* vb  = (const float*)d_in[8];
    const float* gamma = (const float*)d_in[9];
    const float* saw = (const float*)d_in[10];
    float* out = (float*)d_out;
    float* ws = (float*)d_ws;

    float* avg   = ws;                                   // 512
    float* mx    = ws + 512;                             // 512
    float* avg_s = ws + 1024;                            // B*N
    float* max_s = avg_s + (size_t)B * N;                // B*N
    unsigned short* qT  = (unsigned short*)(max_s + (size_t)B * N);  // B*N*8 u16
    unsigned short* kT  = qT + (size_t)B * N * 8;                    // B*N*8 u16
    unsigned short* vbf = kT + (size_t)B * N * 8;                    // B*C*N u16
    float* pA = (float*)(vbf + (size_t)B * C * N);       // B*S*C*N f32 (planar)

    size_t fixed_bytes = (size_t)((char*)pA - (char*)ws);
    int S = 4;
    if (fixed_bytes + (size_t)B * 4 * N * (C + 2) * 4 > ws_size) S = 2;
    if (fixed_bytes + (size_t)B * 2 * N * (C + 2) * 4 > ws_size) S = 1;
    float* pM = pA + (size_t)B * S * C * N;              // B*S*N
    float* pL = pM + (size_t)B * S * N;                  // B*S*N

    k_red_qkv<<<dim3(C, B), 256, 0, stream>>>(x, qw, qb, kw, kb, vw, vb, gamma,
                                              avg, mx, qT, kT, vbf);
    if (S == 4) {
        k_stats_flash<4><<<dim3(N / 128, B, 4), 256, 0, stream>>>(
            x, avg, mx, fc1, fc2, saw, gamma, qT, kT, vbf, avg_s, max_s, pA, pM, pL, out);
        k_out<4><<<dim3(N / 256, B), 256, 0, stream>>>(
            x, avg, mx, fc1, fc2, avg_s, max_s, saw, gamma, pA, pM, pL, out);
    } else if (S == 2) {
        k_stats_flash<2><<<dim3(N / 128, B, 2), 256, 0, stream>>>(
            x, avg, mx, fc1, fc2, saw, gamma, qT, kT, vbf, avg_s, max_s, pA, pM, pL, out);
        k_out<2><<<dim3(N / 256, B), 256, 0, stream>>>(
            x, avg, mx, fc1, fc2, avg_s, max_s, saw, gamma, pA, pM, pL, out);
    } else {
        k_stats_flash<1><<<dim3(N / 128, B, 1), 256, 0, stream>>>(
            x, avg, mx, fc1, fc2, saw, gamma, qT, kT, vbf, avg_s, max_s, pA, pM, pL, out);
        k_out<1><<<dim3(N / 256, B), 256, 0, stream>>>(
            x, avg, mx, fc1, fc2, avg_s, max_s, saw, gamma, pA, pM, pL, out);
    }
}

// Round 11
// 97.064 us; speedup vs baseline: 1.1522x; 1.1522x over previous
//
#include <hip/hip_runtime.h>
#include <math.h>

#define B 8
#define C 64
#define HH 64
#define WW 64
#define N 4096
#define CR 8

typedef __attribute__((ext_vector_type(8))) short short8;
typedef __attribute__((ext_vector_type(4))) float f32x4;

__device__ __forceinline__ float sigmoidf_(float x) { return 1.0f / (1.0f + __expf(-x)); }

// round-float-to-bf16 bits (round-half-up; inputs are finite, well-scaled)
__device__ __forceinline__ unsigned int bfr_(float x) {
    return (__float_as_uint(x) + 0x8000u) >> 16;
}

// ---------------------------------------------------------------------------
// Shared helper: per-batch channel-attention MLP, recomputed redundantly per
// block (2K FLOPs). Requires 256 threads; leaves result in lca[C].
// ---------------------------------------------------------------------------
__device__ __forceinline__ void compute_ca_(const float* __restrict__ avg,
                                            const float* __restrict__ mx,
                                            const float* __restrict__ fc1,
                                            const float* __restrict__ fc2,
                                            int b, float* lca, float* lh) {
    int t = threadIdx.x;
    if (t < 16) {
        int r = t & 7;
        const float* src = (t < 8) ? (avg + b * C) : (mx + b * C);
        float acc = 0.f;
        for (int c2 = 0; c2 < C; c2++) acc += src[c2] * fc1[r * C + c2];
        lh[t] = fmaxf(acc, 0.f);
    }
    __syncthreads();
    if (t < C) {
        float acc = 0.f;
        #pragma unroll
        for (int r = 0; r < CR; r++) acc += (lh[r] + lh[CR + r]) * fc2[t * CR + r];
        lca[t] = sigmoidf_(acc);
    }
    __syncthreads();
}

// ---------------------------------------------------------------------------
// K1: per-(b,c) mean/max reduction  ∪  QKV projection (gamma!=0 only).
// grid (64, 8) x 256.
// ---------------------------------------------------------------------------
__global__ __launch_bounds__(256) void k_red_qkv(const float* __restrict__ x,
                                                 const float* __restrict__ qw, const float* __restrict__ qb,
                                                 const float* __restrict__ kw, const float* __restrict__ kb,
                                                 const float* __restrict__ vw, const float* __restrict__ vb,
                                                 const float* __restrict__ gamma,
                                                 float* __restrict__ avg, float* __restrict__ mx,
                                                 unsigned short* __restrict__ qT,
                                                 unsigned short* __restrict__ kT,
                                                 unsigned short* __restrict__ vbf) {
    const int b = blockIdx.y, cx = blockIdx.x;
    const int t = threadIdx.x;
    {
        const float4* xp = (const float4*)(x + ((size_t)b * C + cx) * N);
        float s = 0.f, m = -INFINITY;
        for (int i = t; i < N / 4; i += 256) {
            float4 v = xp[i];
            s += v.x + v.y + v.z + v.w;
            m = fmaxf(m, fmaxf(fmaxf(v.x, v.y), fmaxf(v.z, v.w)));
        }
        for (int off = 32; off; off >>= 1) {
            s += __shfl_down(s, off);
            m = fmaxf(m, __shfl_down(m, off));
        }
        __shared__ float ls[4], lm[4];
        int wave = t >> 6;
        if ((t & 63) == 0) { ls[wave] = s; lm[wave] = m; }
        __syncthreads();
        if (t == 0) {
            avg[b * C + cx] = (ls[0] + ls[1] + ls[2] + ls[3]) / (float)N;
            mx[b * C + cx] = fmaxf(fmaxf(lm[0], lm[1]), fmaxf(lm[2], lm[3]));
        }
    }
    if (gamma[0] == 0.f) return;  // PAM branch contributes 0; QKV outputs unused
    __shared__ float xl[C][64];
    __shared__ float vwt[C][68];
    __shared__ float qwl[CR * C], kwl[CR * C];
    const int p0 = cx * 64;
    for (int idx = t; idx < C * 64; idx += 256) {
        int c2 = idx >> 6, pix = idx & 63;
        xl[c2][pix] = x[((size_t)b * C + c2) * N + p0 + pix];
    }
    for (int idx = t; idx < C * C; idx += 256) {
        int co = idx >> 6, ci = idx & 63;
        vwt[ci][co] = vw[idx];
    }
    for (int idx = t; idx < CR * C; idx += 256) {
        qwl[idx] = qw[idx];
        kwl[idx] = kw[idx];
    }
    __syncthreads();
    int pix = t & 63, quarter = t >> 6;
    float accv[16];
    #pragma unroll
    for (int i = 0; i < 16; i++) accv[i] = 0.f;
    float accq0 = 0.f, accq1 = 0.f, acck0 = 0.f, acck1 = 0.f;
    for (int ci = 0; ci < C; ci++) {
        float xv = xl[ci][pix];
        accq0 += qwl[(quarter * 2 + 0) * C + ci] * xv;
        accq1 += qwl[(quarter * 2 + 1) * C + ci] * xv;
        acck0 += kwl[(quarter * 2 + 0) * C + ci] * xv;
        acck1 += kwl[(quarter * 2 + 1) * C + ci] * xv;
        const float4* row = (const float4*)&vwt[ci][quarter * 16];
        #pragma unroll
        for (int m2 = 0; m2 < 4; m2++) {
            float4 w4 = row[m2];
            accv[m2 * 4 + 0] += w4.x * xv;
            accv[m2 * 4 + 1] += w4.y * xv;
            accv[m2 * 4 + 2] += w4.z * xv;
            accv[m2 * 4 + 3] += w4.w * xv;
        }
    }
    int pg = p0 + pix;
    int r0 = quarter * 2;
    unsigned int qpk = bfr_(accq0 + qb[r0]) | (bfr_(accq1 + qb[r0 + 1]) << 16);
    unsigned int kpk = bfr_(acck0 + kb[r0]) | (bfr_(acck1 + kb[r0 + 1]) << 16);
    *(unsigned int*)(qT + ((size_t)b * N + pg) * 8 + r0) = qpk;
    *(unsigned int*)(kT + ((size_t)b * N + pg) * 8 + r0) = kpk;
    #pragma unroll
    for (int i = 0; i < 16; i++) {
        int co = quarter * 16 + i;
        vbf[((size_t)b * C + co) * N + pg] = (unsigned short)bfr_(accv[i] + vb[co]);
    }
}

// ---------------------------------------------------------------------------
// K2: (z==0) ca-MLP + per-pixel channel mean/max  ∪  MFMA flash (gamma!=0).
// grid (32, B, S) x 256. z==0 blocks handle stats for pixels [x*128,+128).
// Flash body identical to round-6/7/8 passing version (kf zero-init is
// load-bearing: stale-register NaN*0=NaN inside MFMA).
// Partials PLANAR: pA[(b*S+p)*C + c][n], pM/pL[(b*S+p)][n].
// ---------------------------------------------------------------------------
template <int S>
__global__ __launch_bounds__(256, 2) void k_stats_flash(
    const float* __restrict__ x,
    const float* __restrict__ avg, const float* __restrict__ mx,
    const float* __restrict__ fc1, const float* __restrict__ fc2,
    const float* __restrict__ gamma,
    const unsigned short* __restrict__ qT,
    const unsigned short* __restrict__ kT,
    const unsigned short* __restrict__ vbf,
    float* __restrict__ avg_s, float* __restrict__ max_s,
    float* __restrict__ pA, float* __restrict__ pM, float* __restrict__ pL) {
    __shared__ unsigned short p_lds[4][32 * 64];  // flash P buffer, per-wave 4KB
    __shared__ float lca[C], lh[16];
    const int b = blockIdx.y, p = blockIdx.z;
    const int tid = threadIdx.x;
    if (p == 0) {
        compute_ca_(avg, mx, fc1, fc2, b, lca, lh);
        // stats: 2 threads per pixel (adjacent lanes), 128 pixels per block
        int pix = blockIdx.x * 128 + (tid >> 1);
        int half = tid & 1;
        const float* xb = x + (size_t)b * C * N + pix;
        float s = 0.f, m = -INFINITY;
        for (int c = half * 32; c < half * 32 + 32; c++) {
            float v = xb[(size_t)c * N] * lca[c];
            s += v;
            m = fmaxf(m, v);
        }
        s += __shfl_xor(s, 1);
        m = fmaxf(m, __shfl_xor(m, 1));
        if (half == 0) {
            avg_s[b * N + pix] = s / (float)C;
            max_s[b * N + pix] = m;
        }
    }
    if (gamma[0] == 0.f) return;  // PAM branch contributes 0
    // --- flash body ---
    const int w = tid >> 6, lane = tid & 63;
    const int l16 = lane & 15, grp = lane >> 4;
    const int i0 = blockIdx.x * 128 + w * 32;
    char* pbase = (char*)&p_lds[w][0];
    const int swz = (l16 & 7) << 4;

    short8 qf[2];
    #pragma unroll
    for (int ifr = 0; ifr < 2; ifr++) {
        qf[ifr] = short8{};
        if (grp == 0) qf[ifr] = *(const short8*)(qT + ((size_t)b * N + i0 + ifr * 16 + l16) * 8);
    }
    f32x4 acc[2][4];
    #pragma unroll
    for (int ifr = 0; ifr < 2; ifr++)
        #pragma unroll
        for (int cf = 0; cf < 4; cf++) acc[ifr][cf] = f32x4{0.f, 0.f, 0.f, 0.f};
    float m[2] = {-INFINITY, -INFINITY}, l[2] = {0.f, 0.f};

    const int L = N / S;
    const int T = L / 64;
    const int jbase = p * L;
    const unsigned short* vbase = vbf + (size_t)b * C * N;
    const unsigned short* kbase = kT + (size_t)b * N * 8;

    // zero-init ALL lanes (non-grp0 stay zero; stale NaN*0=NaN otherwise)
    short8 kf[2][4];
    #pragma unroll
    for (int ss = 0; ss < 2; ss++)
        #pragma unroll
        for (int jf = 0; jf < 4; jf++) kf[ss][jf] = short8{};
    #pragma unroll
    for (int jf = 0; jf < 4; jf++) {
        if (grp == 0) kf[0][jf] = *(const short8*)(kbase + (size_t)(jbase + jf * 16 + l16) * 8);
    }

    #pragma unroll 2
    for (int t = 0; t < T; t++) {
        const int cur = t & 1, nxt = cur ^ 1;
        const int j0 = jbase + t * 64;
        short8 vf[2][4];
        #pragma unroll
        for (int h = 0; h < 2; h++)
            #pragma unroll
            for (int cf = 0; cf < 4; cf++)
                vf[h][cf] = *(const short8*)(vbase + (size_t)(cf * 16 + l16) * N + j0 + h * 32 + grp * 8);
        if (t + 1 < T) {
            #pragma unroll
            for (int jf = 0; jf < 4; jf++) {
                if (grp == 0) kf[nxt][jf] = *(const short8*)(kbase + (size_t)(j0 + 64 + jf * 16 + l16) * 8);
            }
        }
        #pragma unroll
        for (int ifr = 0; ifr < 2; ifr++) {
            f32x4 e[4];
            #pragma unroll
            for (int jf = 0; jf < 4; jf++)
                e[jf] = __builtin_amdgcn_mfma_f32_16x16x32_bf16(kf[cur][jf], qf[ifr],
                                                                f32x4{0.f, 0.f, 0.f, 0.f}, 0, 0, 0);
            float tmax = -INFINITY;
            #pragma unroll
            for (int jf = 0; jf < 4; jf++)
                tmax = fmaxf(tmax, fmaxf(fmaxf(e[jf][0], e[jf][1]), fmaxf(e[jf][2], e[jf][3])));
            tmax = fmaxf(tmax, __shfl_xor(tmax, 16));
            tmax = fmaxf(tmax, __shfl_xor(tmax, 32));
            float mnew = fmaxf(m[ifr], tmax);
            float scale = __expf(m[ifr] - mnew);
            float ladd = 0.f;
            unsigned int pk[8];
            #pragma unroll
            for (int jf = 0; jf < 4; jf++) {
                float p0 = __expf(e[jf][0] - mnew);
                float p1 = __expf(e[jf][1] - mnew);
                float p2 = __expf(e[jf][2] - mnew);
                float p3 = __expf(e[jf][3] - mnew);
                ladd += (p0 + p1) + (p2 + p3);
                pk[jf * 2 + 0] = bfr_(p0) | (bfr_(p1) << 16);
                pk[jf * 2 + 1] = bfr_(p2) | (bfr_(p3) << 16);
            }
            ladd += __shfl_xor(ladd, 16);
            ladd += __shfl_xor(ladd, 32);
            l[ifr] = l[ifr] * scale + ladd;
            m[ifr] = mnew;
            #pragma unroll
            for (int cf = 0; cf < 4; cf++) {
                acc[ifr][cf][0] *= scale; acc[ifr][cf][1] *= scale;
                acc[ifr][cf][2] *= scale; acc[ifr][cf][3] *= scale;
            }
            const int rowoff = (ifr * 16 + l16) * 128;
            #pragma unroll
            for (int jf = 0; jf < 4; jf++) {
                int j = jf * 16 + grp * 4;
                *(unsigned int*)(pbase + ((rowoff + (j + 0) * 2) ^ swz)) = pk[jf * 2 + 0];
                *(unsigned int*)(pbase + ((rowoff + (j + 2) * 2) ^ swz)) = pk[jf * 2 + 1];
            }
        }
        #pragma unroll
        for (int ifr = 0; ifr < 2; ifr++) {
            const int rowoff = (ifr * 16 + l16) * 128;
            #pragma unroll
            for (int h = 0; h < 2; h++) {
                short8 pf = *(const short8*)(pbase + ((rowoff + (h * 32 + grp * 8) * 2) ^ swz));
                #pragma unroll
                for (int cf = 0; cf < 4; cf++)
                    acc[ifr][cf] = __builtin_amdgcn_mfma_f32_16x16x32_bf16(vf[h][cf], pf, acc[ifr][cf], 0, 0, 0);
            }
        }
    }
    const size_t plane = (size_t)(b * S + p);
    #pragma unroll
    for (int ifr = 0; ifr < 2; ifr++) {
        const int iglob = i0 + ifr * 16 + l16;
        #pragma unroll
        for (int cf = 0; cf < 4; cf++)
            #pragma unroll
            for (int r = 0; r < 4; r++)
                pA[(plane * C + cf * 16 + grp * 4 + r) * N + iglob] = acc[ifr][cf][r];
        if (grp == 0) {
            pM[plane * N + iglob] = m[ifr];
            pL[plane * N + iglob] = l[ifr];
        }
    }
}

// ---------------------------------------------------------------------------
// K3: conv7x7+sigmoid (from avg_s/max_s halo in LDS) + ca recompute + combine.
// grid (16, B) x 256 (4 rows per block, 10-row halo, zero-padded).
// out = x*(1 + ca*sig(sa)) + gamma*pam; pam partials only read when gamma!=0.
// ---------------------------------------------------------------------------
template <int S>
__global__ __launch_bounds__(256) void k_out(const float* __restrict__ x,
                                             const float* __restrict__ avg, const float* __restrict__ mx,
                                             const float* __restrict__ fc1, const float* __restrict__ fc2,
                                             const float* __restrict__ avg_s, const float* __restrict__ max_s,
                                             const float* __restrict__ saw,
                                             const float* __restrict__ gamma,
                                             const float* __restrict__ pA, const float* __restrict__ pM,
                                             const float* __restrict__ pL,
                                             float* __restrict__ out) {
    const int b = blockIdx.y;
    const int i0 = blockIdx.x * 256;
    const int t = threadIdx.x;
    __shared__ float lca[C], lh[16], lw[98];
    __shared__ float sA[10 * 64], sM[10 * 64];
    if (t < 98) lw[t] = saw[t];
    compute_ca_(avg, mx, fc1, fc2, b, lca, lh);
    // load 10-row halo of stats (rows h0-3 .. h0+6), zero-padded
    const int h0 = i0 >> 6;
    for (int idx = t; idx < 10 * 64; idx += 256) {
        int r = idx >> 6, wcol = idx & 63;
        int hh = h0 - 3 + r;
        float a = 0.f, mm2 = 0.f;
        if (hh >= 0 && hh < HH) {
            a = avg_s[b * N + hh * WW + wcol];
            mm2 = max_s[b * N + hh * WW + wcol];
        }
        sA[idx] = a;
        sM[idx] = mm2;
    }
    __syncthreads();
    // conv for this thread's pixel
    const int lr = (t >> 6) + 3;  // halo-buffer row of this pixel
    const int wc = t & 63;
    float acc = 0.f;
    #pragma unroll
    for (int ky = 0; ky < 7; ky++) {
        #pragma unroll
        for (int kx = 0; kx < 7; kx++) {
            int ww = wc + kx - 3;
            if (ww < 0 || ww >= WW) continue;
            int idx = (lr + ky - 3) * 64 + ww;
            acc += sA[idx] * lw[ky * 7 + kx] + sM[idx] * lw[49 + ky * 7 + kx];
        }
    }
    const float sg = sigmoidf_(acc);
    const int i = i0 + t;
    const float g = gamma[0];
    if (g == 0.f) {
        for (int c = 0; c < C; c++) {
            size_t off = ((size_t)b * C + c) * N + i;
            out[off] = x[off] * (1.f + lca[c] * sg);
        }
        return;
    }
    float mm[S];
    float M = -INFINITY;
    #pragma unroll
    for (int p2 = 0; p2 < S; p2++) {
        mm[p2] = pM[(size_t)(b * S + p2) * N + i];
        M = fmaxf(M, mm[p2]);
    }
    float w[S];
    float lt = 0.f;
    #pragma unroll
    for (int p2 = 0; p2 < S; p2++) {
        w[p2] = __expf(mm[p2] - M);
        lt += w[p2] * pL[(size_t)(b * S + p2) * N + i];
    }
    float inv = 1.0f / lt;
    for (int c = 0; c < C; c++) {
        float a = 0.f;
        #pragma unroll
        for (int p2 = 0; p2 < S; p2++)
            a += w[p2] * pA[((size_t)(b * S + p2) * C + c) * N + i];
        float pam = a * inv;
        size_t off = ((size_t)b * C + c) * N + i;
        out[off] = x[off] * (1.f + lca[c] * sg) + g * pam;
    }
}

extern "C" void kernel_launch(void* const* d_in, const int* in_sizes, int n_in,
                              void* d_out, int out_size, void* d_ws, size_t ws_size,
                              hipStream_t stream) {
    (void)in_sizes; (void)n_in; (void)out_size;
    const float* x   = (const float*)d_in[0];
    const float* fc1 = (const float*)d_in[1];
    const float* fc2 = (const float*)d_in[2];
    const float* qw  = (const float*)d_in[3];
    const float* qb  = (const float*)d_in[4];
    const float* kw  = (const float*)d_in[5];
    const float* kb  = (const float*)d_in[6];
    const float* vw  = (const float*)d_in[7];
    const float* vb  = (const float*)d_in[8];
    const float* gamma = (const float*)d_in[9];
    const float* saw = (const float*)d_in[10];
    float* out = (float*)d_out;
    float* ws = (float*)d_ws;

    // workspace layout (float units); all sub-bases 16B-aligned
    float* avg   = ws;                                   // 512
    float* mx    = ws + 512;                             // 512
    float* avg_s = ws + 1024;                            // B*N
    float* max_s = avg_s + (size_t)B * N;                // B*N
    unsigned short* qT  = (unsigned short*)(max_s + (size_t)B * N);  // B*N*8 u16
    unsigned short* kT  = qT + (size_t)B * N * 8;                    // B*N*8 u16
    unsigned short* vbf = kT + (size_t)B * N * 8;                    // B*C*N u16
    float* pA = (float*)(vbf + (size_t)B * C * N);       // B*S*C*N f32 (planar)

    size_t fixed_bytes = (size_t)((char*)pA - (char*)ws);
    int S = 4;
    if (fixed_bytes + (size_t)B * 4 * N * (C + 2) * 4 > ws_size) S = 2;
    if (fixed_bytes + (size_t)B * 2 * N * (C + 2) * 4 > ws_size) S = 1;
    float* pM = pA + (size_t)B * S * C * N;              // B*S*N
    float* pL = pM + (size_t)B * S * N;                  // B*S*N

    k_red_qkv<<<dim3(C, B), 256, 0, stream>>>(x, qw, qb, kw, kb, vw, vb, gamma,
                                              avg, mx, qT, kT, vbf);
    if (S == 4) {
        k_stats_flash<4><<<dim3(N / 128, B, 4), 256, 0, stream>>>(
            x, avg, mx, fc1, fc2, gamma, qT, kT, vbf, avg_s, max_s, pA, pM, pL);
        k_out<4><<<dim3(N / 256, B), 256, 0, stream>>>(
            x, avg, mx, fc1, fc2, avg_s, max_s, saw, gamma, pA, pM, pL, out);
    } else if (S == 2) {
        k_stats_flash<2><<<dim3(N / 128, B, 2), 256, 0, stream>>>(
            x, avg, mx, fc1, fc2, gamma, qT, kT, vbf, avg_s, max_s, pA, pM, pL);
        k_out<2><<<dim3(N / 256, B), 256, 0, stream>>>(
            x, avg, mx, fc1, fc2, avg_s, max_s, saw, gamma, pA, pM, pL, out);
    } else {
        k_stats_flash<1><<<dim3(N / 128, B, 1), 256, 0, stream>>>(
            x, avg, mx, fc1, fc2, gamma, qT, kT, vbf, avg_s, max_s, pA, pM, pL);
        k_out<1><<<dim3(N / 256, B), 256, 0, stream>>>(
            x, avg, mx, fc1, fc2, avg_s, max_s, saw, gamma, pA, pM, pL, out);
    }
}